// Round 11
// baseline (583.700 us; speedup 1.0000x reference)
//
#include <hip/hip_runtime.h>

// MOTCAT_Surv R11. R10: 554 us, screen2 173 us (Occ 20%, VALUBusy 52%, MfmaUtil 8%)
// -> latency/VALU bound at 2 blocks/CU. R11: (a) screen3: 8 column-splits (4 blocks/CU,
// 16 waves/CU) + double-buffered B tile (1 barrier/iter), candidates 8x8=64/row as u16;
// (b) gemmV: k-major As + float4 LDS reads (was scalar-read bound); (c) stageD widened
// to 64 candidates. Selection correctness unchanged: per-64-col-slice top-8 (margin 2
// over needed 6 vs bf16 noise) -> merged top-8/split -> fp64 rescore picks exact top-6.

typedef __attribute__((ext_vector_type(8))) short short8;
typedef __attribute__((ext_vector_type(4))) short short4v;
typedef __attribute__((ext_vector_type(4))) float f32x4;

__device__ inline float bf2f(unsigned short b) {
    unsigned u = ((unsigned)b) << 16;
    return __builtin_bit_cast(float, u);
}
__device__ inline unsigned short f2bf(float f) {   // round-to-nearest-even
    unsigned u = __builtin_bit_cast(unsigned, f);
    unsigned r = u + 0x7fffu + ((u >> 16) & 1u);
    return (unsigned short)(r >> 16);
}
__device__ inline f32x4 mfma16(short8 a, short8 b, f32x4 c) {
    return __builtin_amdgcn_mfma_f32_16x16x32_bf16(a, b, c, 0, 0, 0);
}
// A-frag: lane holds A[m=lane&15][k=(lane>>4)*8+j]; B-frag: B[k][n=lane&15];
// C/D: col=lane&15, row=(lane>>4)*4+reg (learn_hip m89).

// ---------------------------------------------------------------------------
// VALU fp32 GEMM: C = act(A@B + bias) (+=C if ACCUM). 64x64 tile, BK=16.
// Both LDS tiles k-major -> inner loop = 2x ds_read_b128 + 16 FMA per k.
// ---------------------------------------------------------------------------
template <int AISBF, int ACT, int ACCUM>
__launch_bounds__(256)
__global__ void gemmV(const void* __restrict__ Av, const float* __restrict__ B,
                      const float* __restrict__ bias, float* __restrict__ C,
                      int M, int N, int K) {
    __shared__ float As[16][68];   // k-major: [k][row]
    __shared__ float Bs[16][68];   // k-major: [k][col]
    const int t = threadIdx.x;
    const int row0 = blockIdx.y * 64, col0 = blockIdx.x * 64;
    const int tx = t & 15, ty = t >> 4;

    float acc[4][4];
    #pragma unroll
    for (int i = 0; i < 4; i++)
        #pragma unroll
        for (int j = 0; j < 4; j++) acc[i][j] = 0.0f;

    for (int kt = 0; kt < K; kt += 16) {
        {   // stage A: 64 rows x 16 k -> As[k][row]
            const int row = t >> 2, kq = (t & 3) * 4;
            if (AISBF) {
                const unsigned short* a16 = (const unsigned short*)Av;
                short4v hv = *(const short4v*)&a16[(size_t)(row0 + row) * K + kt + kq];
                #pragma unroll
                for (int e = 0; e < 4; e++)
                    As[kq + e][row] = bf2f((unsigned short)hv[e]);
            } else {
                const float* a32 = (const float*)Av;
                f32x4 v = *(const f32x4*)&a32[(size_t)(row0 + row) * K + kt + kq];
                #pragma unroll
                for (int e = 0; e < 4; e++) As[kq + e][row] = v[e];
            }
        }
        {   // stage B: 16 k x 64 n
            const int k = t >> 4, n4 = (t & 15) * 4;
            f32x4 v = *(const f32x4*)&B[(size_t)(kt + k) * N + col0 + n4];
            #pragma unroll
            for (int e = 0; e < 4; e++) Bs[k][n4 + e] = v[e];
        }
        __syncthreads();
        #pragma unroll
        for (int kk = 0; kk < 16; kk++) {
            f32x4 av = *(const f32x4*)&As[kk][ty * 4];
            f32x4 bv = *(const f32x4*)&Bs[kk][tx * 4];
            #pragma unroll
            for (int i = 0; i < 4; i++)
                #pragma unroll
                for (int j = 0; j < 4; j++)
                    acc[i][j] += av[i] * bv[j];
        }
        __syncthreads();
    }
    #pragma unroll
    for (int i = 0; i < 4; i++) {
        const int row = row0 + ty * 4 + i;
        #pragma unroll
        for (int j = 0; j < 4; j++) {
            const int col = col0 + tx * 4 + j;
            float v = acc[i][j] + bias[col];
            if (ACT == 1) v = v > 0.0f ? v : 0.01f * v;
            size_t idx = (size_t)row * N + col;
            if (ACCUM) v += C[idx];
            C[idx] = v;
        }
    }
}

// ---------------------------------------------------------------------------
__global__ void colsum_k(const float* __restrict__ x, float* __restrict__ out) {
    int d = threadIdx.x, b = blockIdx.x;
    float s = 0.0f;
    int i0 = b * 128;
    for (int i = 0; i < 128; i++) s += x[(size_t)(i0 + i) * 256 + d];
    out[b * 256 + d] = s;
}
__global__ void meanred_k(const float* __restrict__ p, float* __restrict__ mean) {
    int d = threadIdx.x;
    float s = 0.0f;
    for (int b = 0; b < 64; b++) s += p[b * 256 + d];
    mean[d] = s * (1.0f / 8192.0f);
}
__global__ void finalize_x(float* __restrict__ x, const float* __restrict__ mean) {
    size_t idx = (size_t)blockIdx.x * blockDim.x + threadIdx.x;
    f32x4 v = *(f32x4*)&x[idx * 4];
    int d4 = (int)((idx * 4) & 255);
    f32x4 m = *(const f32x4*)&mean[d4];
    #pragma unroll
    for (int e = 0; e < 4; e++) v[e] = (v[e] + m[e]) * 0.5f;
    *(f32x4*)&x[idx * 4] = v;
}
__global__ void f2bf_k(const float* __restrict__ src, unsigned short* __restrict__ dst, int n4) {
    size_t idx = (size_t)blockIdx.x * blockDim.x + threadIdx.x;
    if (idx >= (size_t)n4) return;
    f32x4 v = *(const f32x4*)&src[idx * 4];
    short4v h;
    #pragma unroll
    for (int e = 0; e < 4; e++) h[e] = (short)f2bf(v[e]);
    *(short4v*)&dst[idx * 4] = h;
}
__global__ void cpy_k(const float* __restrict__ src, float* __restrict__ dst) {
    size_t idx = (size_t)blockIdx.x * blockDim.x + threadIdx.x;
    *(f32x4*)&dst[idx * 4] = *(const f32x4*)&src[idx * 4];
}

// ---------------------------------------------------------------------------
template<int NK>
__device__ inline void insertN(float (&tv)[NK], int (&tj)[NK], float v, int j) {
    #pragma unroll
    for (int k = 0; k < NK; k++) {
        float nxt = (k < NK - 1) ? tv[k + 1] : 3.0e38f;
        int   nj  = (k < NK - 1) ? tj[k + 1] : 0;
        bool shift = (v > nxt);
        bool here  = !shift && (v > tv[k]);
        tv[k] = shift ? nxt : (here ? v : tv[k]);
        tj[k] = shift ? nj  : (here ? j : tj[k]);
    }
}

// ---------------------------------------------------------------------------
// screen3: logits = e_h @ e_t^T (bf16 MFMA), top-8 per column EIGHTH per row.
// Grid (8 splits, 128 row-blocks of 64); 256 thr = 4 waves x 16 rows.
// Double-buffered 32-col B tiles (1 barrier/iter); register top-8 per (lane,row)
// slice; shfl_xor butterfly merge over the 16 col-slice lanes; u16 candidates.
// ---------------------------------------------------------------------------
__launch_bounds__(256, 4)
__global__ void screen3(const unsigned short* __restrict__ eh16,
                        const unsigned short* __restrict__ et16,
                        unsigned short* __restrict__ candi) {
    __shared__ __align__(16) unsigned short Bs[2][32][264];
    const int t = threadIdx.x;
    const int cs = blockIdx.x;          // column eighth: cols [cs*1024, cs*1024+1024)
    const int r0 = blockIdx.y * 64;
    const int w = t >> 6, lid = t & 63, g = lid >> 4, m16 = lid & 15;
    const int ar = w * 16;
    const int sn = t >> 3, so = (t & 7) * 32;   // staging coords

    short8 afr[8];   // this wave's 16 rows, K=256
    #pragma unroll
    for (int ks = 0; ks < 8; ks++)
        afr[ks] = *(const short8*)&eh16[(size_t)(r0 + ar + m16) * 256 + ks * 32 + g * 8];

    float tv[4][8]; int tj[4][8];
    #pragma unroll
    for (int r = 0; r < 4; r++)
        #pragma unroll
        for (int q = 0; q < 8; q++) { tv[r][q] = -3.0e38f; tj[r][q] = 0; }

    {   // stage tile 0 -> buf 0
        const int j0 = cs * 1024;
        #pragma unroll
        for (int c = 0; c < 4; c++)
            *(short8*)&Bs[0][sn][so + c * 8] =
                *(const short8*)&et16[(size_t)(j0 + sn) * 256 + so + c * 8];
    }
    __syncthreads();

    for (int tile = 0; tile < 32; tile++) {
        const int cur = tile & 1;
        const int j0 = cs * 1024 + tile * 32;
        if (tile < 31) {   // stage next tile into the other buffer (overlaps MFMA)
            const int jn = j0 + 32;
            #pragma unroll
            for (int c = 0; c < 4; c++)
                *(short8*)&Bs[cur ^ 1][sn][so + c * 8] =
                    *(const short8*)&et16[(size_t)(jn + sn) * 256 + so + c * 8];
        }
        f32x4 a0 = {0.0f, 0.0f, 0.0f, 0.0f}, a1 = a0;
        #pragma unroll
        for (int ks = 0; ks < 8; ks++) {
            short8 b0 = *(const short8*)&Bs[cur][m16][ks * 32 + g * 8];
            short8 b1 = *(const short8*)&Bs[cur][16 + m16][ks * 32 + g * 8];
            a0 = mfma16(afr[ks], b0, a0);
            a1 = mfma16(afr[ks], b1, a1);
        }
        #pragma unroll
        for (int r = 0; r < 4; r++) {
            float v0 = a0[r];
            if (v0 > tv[r][0]) insertN<8>(tv[r], tj[r], v0, j0 + m16);
            float v1 = a1[r];
            if (v1 > tv[r][0]) insertN<8>(tv[r], tj[r], v1, j0 + 16 + m16);
        }
        __syncthreads();   // reads of cur done (before next iter overwrites it); next buf staged
    }
    // butterfly merge across the 16 lanes (same w,g) sharing each row
    #pragma unroll
    for (int step = 1; step < 16; step <<= 1) {
        #pragma unroll
        for (int r = 0; r < 4; r++) {
            float ov[8]; int oj[8];
            #pragma unroll
            for (int q = 0; q < 8; q++) {
                ov[q] = __shfl_xor(tv[r][q], step);
                oj[q] = __shfl_xor(tj[r][q], step);
            }
            #pragma unroll
            for (int q = 0; q < 8; q++)
                if (ov[q] > tv[r][0]) insertN<8>(tv[r], tj[r], ov[q], oj[q]);
        }
    }
    if (m16 == 0) {
        #pragma unroll
        for (int r = 0; r < 4; r++) {
            const int row = r0 + ar + g * 4 + r;
            #pragma unroll
            for (int q = 0; q < 8; q++)
                candi[(size_t)row * 64 + cs * 8 + q] = (unsigned short)tj[r][q];
        }
    }
}

// ---------------------------------------------------------------------------
// Stage D: fp64 rescore of 64 candidates (shuffle-reduced), top-6 (tie: lower idx),
// softmax p, message, ka softmax, e_Nh -> m1/m2 bf16. One wave per row.
// ---------------------------------------------------------------------------
__launch_bounds__(64)
__global__ void stageD(const float* __restrict__ eh, const float* __restrict__ et,
                       const unsigned short* __restrict__ candi,
                       unsigned short* __restrict__ m1, unsigned short* __restrict__ m2) {
    const int i = blockIdx.x, l = threadIdx.x;
    __shared__ int sj[64];
    __shared__ double slog[64];
    __shared__ float sred[64 * 12];
    __shared__ float ssum[12];
    __shared__ int selj[6];
    __shared__ float sp[6], skp[6];

    sj[l] = candi[(size_t)i * 64 + l] & 8191;
    __syncthreads();
    f32x4 eh4 = *(const f32x4*)&eh[(size_t)i * 256 + l * 4];

    for (int c = 0; c < 64; c++) {
        const f32x4 t4 = *(const f32x4*)&et[(size_t)sj[c] * 256 + l * 4];
        double p = (double)eh4[0] * t4[0] + (double)eh4[1] * t4[1] +
                   (double)eh4[2] * t4[2] + (double)eh4[3] * t4[3];
        #pragma unroll
        for (int off = 1; off < 64; off <<= 1) p += __shfl_xor(p, off);
        if (l == 0) slog[c] = p * 0.0625;   // SCALE = 1/16
    }
    __syncthreads();
    if (l == 0) {
        unsigned long long used = 0;
        float w6[6];
        for (int s = 0; s < 6; s++) {
            double best = -1.0e300; int bj = 0x7fffffff, bc = 0;
            for (int c = 0; c < 64; c++) {
                if ((used >> c) & 1ull) continue;
                double v = slog[c]; int j = sj[c];
                if (v > best || (v == best && j < bj)) { best = v; bj = j; bc = c; }
            }
            used |= 1ull << bc;
            selj[s] = bj; w6[s] = (float)best;
        }
        float mx = w6[0];
        for (int s = 1; s < 6; s++) mx = fmaxf(mx, w6[s]);
        float se = 0.0f, e6[6];
        for (int s = 0; s < 6; s++) { e6[s] = expf(w6[s] - mx); se += e6[s]; }
        for (int s = 0; s < 6; s++) sp[s] = e6[s] / se;
    }
    __syncthreads();
    f32x4 nb[6];
    #pragma unroll
    for (int k = 0; k < 6; k++) nb[k] = *(const f32x4*)&et[(size_t)(selj[k] & 8191) * 256 + l * 4];
    #pragma unroll
    for (int k = 0; k < 6; k++) {
        float pk = sp[k];
        float pn = nb[k][0] + nb[k][1] + nb[k][2] + nb[k][3];
        float pg = 0.0f;
        #pragma unroll
        for (int e = 0; e < 4; e++) {
            float ehd = eh4[e], nbd = nb[k][e];
            float ehr = pk * nbd + (1.0f - pk) * ehd;
            pg += tanhf(ehd + ehr);
        }
        sred[l * 12 + k] = pn;
        sred[l * 12 + 6 + k] = pg;
    }
    __syncthreads();
    if (l < 12) {
        float s = 0.0f;
        for (int ll = 0; ll < 64; ll++) s += sred[ll * 12 + l];
        ssum[l] = s;
    }
    __syncthreads();
    if (l == 0) {
        float ka[6], mx = -3.0e38f, se = 0.0f;
        for (int k = 0; k < 6; k++) { ka[k] = ssum[k] * ssum[6 + k]; mx = fmaxf(mx, ka[k]); }
        for (int k = 0; k < 6; k++) { ka[k] = expf(ka[k] - mx); se += ka[k]; }
        for (int k = 0; k < 6; k++) skp[k] = ka[k] / se;
    }
    __syncthreads();
    f32x4 enh = {0.0f, 0.0f, 0.0f, 0.0f};
    #pragma unroll
    for (int k = 0; k < 6; k++) {
        float kp = skp[k];
        #pragma unroll
        for (int e = 0; e < 4; e++) enh[e] += kp * nb[k][e];
    }
    short4v h1, h2;
    #pragma unroll
    for (int e = 0; e < 4; e++) {
        h1[e] = (short)f2bf(eh4[e] + enh[e]);
        h2[e] = (short)f2bf(eh4[e] * enh[e]);
    }
    *(short4v*)&m1[(size_t)i * 256 + l * 4] = h1;
    *(short4v*)&m2[(size_t)i * 256 + l * 4] = h2;
}

// ---------------------------------------------------------------------------
// Readout
// ---------------------------------------------------------------------------
__launch_bounds__(256)
__global__ void gate2_k(const float* __restrict__ g1, const float* __restrict__ Ag2,
                        const float* __restrict__ bg2, float* __restrict__ glog) {
    const int i = blockIdx.x * 256 + threadIdx.x;
    float s = 0.0f;
    #pragma unroll 4
    for (int h = 0; h < 128; h++) s += g1[(size_t)i * 128 + h] * Ag2[h];
    glog[i] = s + bg2[0];
}

__launch_bounds__(1024)
__global__ void softmax_g(const float* __restrict__ glog, float* __restrict__ gexp,
                          float* __restrict__ scal) {
    const int t = threadIdx.x;
    __shared__ float red[1024];
    float v[8];
    float m = -3.0e38f;
    #pragma unroll
    for (int c = 0; c < 8; c++) { v[c] = glog[t + c * 1024]; m = fmaxf(m, v[c]); }
    red[t] = m; __syncthreads();
    for (int st = 512; st > 0; st >>= 1) {
        if (t < st) red[t] = fmaxf(red[t], red[t + st]);
        __syncthreads();
    }
    float gm = red[0]; __syncthreads();
    float s = 0.0f;
    #pragma unroll
    for (int c = 0; c < 8; c++) {
        float e = expf(v[c] - gm);
        gexp[t + c * 1024] = e;
        s += e;
    }
    red[t] = s; __syncthreads();
    for (int st = 512; st > 0; st >>= 1) {
        if (t < st) red[t] += red[t + st];
        __syncthreads();
    }
    if (t == 0) scal[0] = 1.0f / red[0];
}

__launch_bounds__(256)
__global__ void wsum_k(const float* __restrict__ emsg, const float* __restrict__ gexp,
                       float* __restrict__ egp) {
    const int b = blockIdx.x, d = threadIdx.x;
    float s = 0.0f;
    const int i0 = b * 128;
    for (int i = 0; i < 128; i++) s += gexp[i0 + i] * emsg[(size_t)(i0 + i) * 256 + d];
    egp[b * 256 + d] = s;
}
__global__ void egfinal_f(const float* __restrict__ egp, const float* __restrict__ scal,
                          float* __restrict__ out) {
    const int d = threadIdx.x;
    float s = 0.0f;
    for (int b = 0; b < 64; b++) s += egp[b * 256 + d];
    out[d] = s * scal[0];
}

__global__ void wsbad_k(float* __restrict__ out) { out[3] = 9000.0f; }

// ---------------------------------------------------------------------------
extern "C" void kernel_launch(void* const* d_in, const int* in_sizes, int n_in,
                              void* d_out, int out_size, void* d_ws, size_t ws_size,
                              hipStream_t stream) {
    (void)in_sizes; (void)n_in; (void)out_size;
    const float* x_path = (const float*)d_in[0];
    const float* fc1_W  = (const float*)d_in[1];
    const float* fc1_b  = (const float*)d_in[2];
    const float* Wh     = (const float*)d_in[3];
    const float* bh     = (const float*)d_in[4];
    const float* Wt     = (const float*)d_in[5];
    const float* bt     = (const float*)d_in[6];
    const float* W1     = (const float*)d_in[7];
    const float* b1     = (const float*)d_in[8];
    const float* W2     = (const float*)d_in[9];
    const float* b2     = (const float*)d_in[10];
    const float* Ag1    = (const float*)d_in[11];
    const float* bg1    = (const float*)d_in[12];
    const float* Ag2    = (const float*)d_in[13];
    const float* bg2    = (const float*)d_in[14];
    float* out_f = (float*)d_out;   // fp32: e_msg [0,2097152), e_g [2097152,2097408)

    const size_t WS_NEEDED = 26412048;
    if (ws_size < WS_NEEDED) {
        hipLaunchKernelGGL(wsbad_k, dim3(1), dim3(1), 0, stream, out_f);
        return;
    }

    char* ws = (char*)d_ws;
    float* x     = (float*)(ws + 0);
    unsigned short* eh16 = (unsigned short*)(ws + 0);
    unsigned short* et16 = (unsigned short*)(ws + 4194304);
    unsigned short* m1b  = (unsigned short*)(ws + 0);
    unsigned short* m2b  = (unsigned short*)(ws + 4194304);
    float* g1    = (float*)(ws + 0);          // 8192x128 fp32 (after m1b/m2b dead)
    float* eh    = (float*)(ws + 8388608);
    float* emsg  = (float*)(ws + 8388608);
    float* et    = (float*)(ws + 16777216);
    unsigned short* candi = (unsigned short*)(ws + 25165824);   // 8192x64 u16 = 1 MB
    float* meanp = (float*)(ws + 26214400);
    float* meanv = (float*)(ws + 26279936);
    float* glog  = (float*)(ws + 26280960);
    float* gexp  = (float*)(ws + 26313728);
    float* egp   = (float*)(ws + 26346496);
    float* scal  = (float*)(ws + 26412032);

    dim3 gg(4, 128);
    // 1) x = leaky(x_path @ fc1_W + fc1_b)
    hipLaunchKernelGGL((gemmV<0, 1, 0>), gg, dim3(256), 0, stream,
                       (const void*)x_path, fc1_W, fc1_b, x, 8192, 256, 1024);
    // 2) x = (x + mean(x)) * 0.5
    hipLaunchKernelGGL(colsum_k, dim3(64), dim3(256), 0, stream, x, meanp);
    hipLaunchKernelGGL(meanred_k, dim3(1), dim3(256), 0, stream, meanp, meanv);
    hipLaunchKernelGGL(finalize_x, dim3(2048), dim3(256), 0, stream, x, meanv);
    // 3) e_h, e_t (fp32 exact)
    hipLaunchKernelGGL((gemmV<0, 0, 0>), gg, dim3(256), 0, stream,
                       (const void*)x, Wh, bh, eh, 8192, 256, 256);
    hipLaunchKernelGGL((gemmV<0, 0, 0>), gg, dim3(256), 0, stream,
                       (const void*)x, Wt, bt, et, 8192, 256, 256);
    // 4) bf16 copies for screening
    hipLaunchKernelGGL(f2bf_k, dim3(2048), dim3(256), 0, stream, eh, eh16, 524288);
    hipLaunchKernelGGL(f2bf_k, dim3(2048), dim3(256), 0, stream, et, et16, 524288);
    // 5) screening: 8 splits x top-8 -> 64 candidates/row (u16)
    hipLaunchKernelGGL(screen3, dim3(8, 128), dim3(256), 0, stream, eh16, et16, candi);
    // 6) fp64 select + message -> m1b/m2b
    hipLaunchKernelGGL(stageD, dim3(8192), dim3(64), 0, stream, eh, et, candi, m1b, m2b);
    // 7) e_msg = leaky(m1@W1+b1) + leaky(m2@W2+b2)
    hipLaunchKernelGGL((gemmV<1, 1, 0>), gg, dim3(256), 0, stream,
                       (const void*)m1b, W1, b1, emsg, 8192, 256, 256);
    hipLaunchKernelGGL((gemmV<1, 1, 1>), gg, dim3(256), 0, stream,
                       (const void*)m2b, W2, b2, emsg, 8192, 256, 256);
    // 8) output 0: e_msg fp32
    hipLaunchKernelGGL(cpy_k, dim3(2048), dim3(256), 0, stream, emsg, out_f);
    // 9) readout
    hipLaunchKernelGGL((gemmV<0, 1, 0>), dim3(2, 128), dim3(256), 0, stream,
                       (const void*)emsg, Ag1, bg1, g1, 8192, 128, 256);
    hipLaunchKernelGGL(gate2_k, dim3(32), dim3(256), 0, stream, g1, Ag2, bg2, glog);
    hipLaunchKernelGGL(softmax_g, dim3(1), dim3(1024), 0, stream, glog, gexp, scal);
    hipLaunchKernelGGL(wsum_k, dim3(64), dim3(256), 0, stream, emsg, gexp, egp);
    hipLaunchKernelGGL(egfinal_f, dim3(1), dim3(256), 0, stream, egp, scal, out_f + 2097152);
}